// Round 4
// baseline (187.198 us; speedup 1.0000x reference)
//
#include <hip/hip_runtime.h>

#define HID 768
#define NTHREADS 256
#define WPB 4          // waves per block = steps processed in parallel per token

// One block per token t; wave w handles path steps d = w, w+4, w+8, ...
//
// v4 -> v5: fuse the reduce. Each block combines its 4 wave-sums in LDS
// into ONE token-partial (tree (w0+w1)+(w2+w3), identical to the old
// reduce kernel's float4 (x+y)+(z+w)), stores it AGENT-scope-atomically,
// then release-increments a counter; the last block acquire-loads all T
// partials (ascending stride-256 order + the same 6-level butterfly +
// 4-slot combine as the old reduce kernel => bit-identical final sum)
// and writes out[0]. Counter is zeroed by a 4-byte hipMemsetAsync, so
// the dispatch count is unchanged while the second kernel's ~3-4 us
// launch+latency and its inter-dispatch gap disappear.
__global__ __launch_bounds__(NTHREADS, 8) void huffman_token_kernel(
    const float* __restrict__ hidden,       // [T, H]
    const int*   __restrict__ target,       // [T]
    const float* __restrict__ node_W,       // [V-1, H, 2]
    const float* __restrict__ node_b,       // [V-1, 2]
    const int*   __restrict__ path_nodes,   // [V, D]
    const int*   __restrict__ path_bits,    // [V, D]
    const void*  __restrict__ path_mask,    // [V, D] bool (byte OR int32 layout)
    float*       __restrict__ partial,      // [T] token partials (in ws)
    int*         __restrict__ counter,      // [1] zeroed by memset (in ws)
    float*       __restrict__ out,          // [1] final loss
    int D, int T)
{
    const int t    = blockIdx.x;
    const int wave = threadIdx.x >> 6;
    const int lane = threadIdx.x & 63;

    __shared__ float ws4[WPB];
    __shared__ int   last_flag;

    // Mask layout detect: mask[0,0..3] all true (min Huffman depth >> 4),
    // so byte layout reads 0x01010101, int32 layout reads 1.
    const bool mask_is_byte = (*(const unsigned int*)path_mask) > 1u;

    const int v = target[t];                     // block-uniform scalar
    const long pbase = (long)v * D;

    // Per-lane path metadata: lane d owns step d (requires D <= 64; here ~20).
    bool  my_m = false;
    int   my_n = 0, my_bit = 0;
    float my_b0 = 0.0f, my_b1 = 0.0f;
    if (lane < D) {
        my_m = mask_is_byte
            ? (((const unsigned char*)path_mask)[pbase + lane] != 0)
            : (((const int*)path_mask)[pbase + lane] != 0);
        if (my_m) {
            my_n   = path_nodes[pbase + lane];
            my_bit = path_bits[pbase + lane];
            const float2 b2 = ((const float2*)node_b)[my_n];
            my_b0 = b2.x; my_b1 = b2.y;
        }
    }
    const int depth = __popcll(__ballot(my_m));  // mask is a prefix in d

    // h[t] into registers: lane owns k-pairs p = j*64 + lane (k = 2p, 2p+1).
    const float2* __restrict__ h2 = (const float2*)(hidden + (long)t * HID);
    float2 h[6];
    #pragma unroll
    for (int j = 0; j < 6; ++j) h[j] = h2[j * 64 + lane];

    float sum = 0.0f;

    for (int d = wave; d < depth; d += WPB) {
        // Wave-uniform per-step scalars straight into SGPRs.
        const int   n   = __builtin_amdgcn_readlane(my_n, d);
        const int   bit = __builtin_amdgcn_readlane(my_bit, d);
        const float b0  = __uint_as_float(
            __builtin_amdgcn_readlane(__float_as_uint(my_b0), d));
        const float b1  = __uint_as_float(
            __builtin_amdgcn_readlane(__float_as_uint(my_b1), d));

        const float4* __restrict__ w4 =
            (const float4*)(node_W + (long)n * (HID * 2));
        float4 w[6];
        #pragma unroll
        for (int j = 0; j < 6; ++j) w[j] = w4[j * 64 + lane];

        float acc0 = 0.0f, acc1 = 0.0f;
        #pragma unroll
        for (int j = 0; j < 6; ++j) {       // w = W[n,2p,{0,1}], W[n,2p+1,{0,1}]
            acc0 += h[j].x * w[j].x + h[j].y * w[j].z;
            acc1 += h[j].x * w[j].y + h[j].y * w[j].w;
        }

        // Packed 7-shuffle reduction (bit-identical to two 6-level butterflies).
        float r     = (lane < 32) ? acc0 : acc1;
        float other = (lane < 32) ? acc1 : acc0;
        r += __shfl_xor(other, 32, 64);     // fold lane^32 for both outputs
        #pragma unroll
        for (int off = 16; off > 0; off >>= 1) r += __shfl_xor(r, off, 64);
        const float ro = __shfl_xor(r, 32, 64);
        const float A0 = (lane < 32) ? r  : ro;
        const float A1 = (lane < 32) ? ro : r;

        // Double-softmax CE (faithful to reference), redundant per lane.
        const float l0  = A0 + b0;
        const float l1  = A1 + b1;
        const float m   = fmaxf(l0, l1);
        const float e0  = __expf(l0 - m);
        const float e1  = __expf(l1 - m);
        const float s   = e0 + e1;
        const float p0  = e0 / s;
        const float p1  = e1 / s;
        const float lse = __logf(__expf(p0) + __expf(p1));
        const float pb  = bit ? p1 : p0;
        sum += lse - pb;
    }

    // ---- cross-wave combine: token partial = (w0+w1)+(w2+w3), same tree
    //      as the old reduce kernel's float4 (x+y)+(z+w) ----
    if (lane == 0) ws4[wave] = sum;
    __syncthreads();

    if (threadIdx.x == 0) {
        const float tp = (ws4[0] + ws4[1]) + (ws4[2] + ws4[3]);
        __hip_atomic_store(&partial[t], tp, __ATOMIC_RELAXED,
                           __HIP_MEMORY_SCOPE_AGENT);
        const int prev = __hip_atomic_fetch_add(counter, 1, __ATOMIC_ACQ_REL,
                                                __HIP_MEMORY_SCOPE_AGENT);
        last_flag = (prev == gridDim.x - 1);
    }
    __syncthreads();

    if (last_flag) {
        // Final reduce, bit-identical to the old huffman_reduce_kernel:
        // thread tid sums tokens {tid, tid+256, ...} ascending, 6-level
        // butterfly, 4-slot sequential combine.
        float s = 0.0f;
        for (int i = threadIdx.x; i < T; i += NTHREADS)
            s += __hip_atomic_load(&partial[i], __ATOMIC_RELAXED,
                                   __HIP_MEMORY_SCOPE_AGENT);
        #pragma unroll
        for (int off = 32; off > 0; off >>= 1) s += __shfl_xor(s, off, 64);
        __syncthreads();                      // ws4 reuse safe
        if (lane == 0) ws4[wave] = s;
        __syncthreads();
        if (threadIdx.x == 0) {
            float tot = 0.0f;
            #pragma unroll
            for (int w = 0; w < WPB; ++w) tot += ws4[w];
            out[0] = tot;
        }
    }
}

extern "C" void kernel_launch(void* const* d_in, const int* in_sizes, int n_in,
                              void* d_out, int out_size, void* d_ws, size_t ws_size,
                              hipStream_t stream) {
    const float* hidden     = (const float*)d_in[0];
    const int*   target     = (const int*)d_in[1];
    const float* node_W     = (const float*)d_in[2];
    const float* node_b     = (const float*)d_in[3];
    const int*   path_nodes = (const int*)d_in[4];
    const int*   path_bits  = (const int*)d_in[5];
    const void*  path_mask  = (const void*)d_in[6];
    float* out = (float*)d_out;
    float* partial = (float*)d_ws;

    const int T   = in_sizes[0] / HID;        // B*S = 2048 (in_sizes are elem counts)
    const int Vm1 = in_sizes[3] / 2;          // V-1
    const int V   = Vm1 + 1;
    const int D   = in_sizes[4] / V;          // padded path depth (~20)

    int* counter = (int*)(partial + T);       // 4 bytes of ws past the partials

    hipMemsetAsync(counter, 0, sizeof(int), stream);

    huffman_token_kernel<<<dim3(T), dim3(NTHREADS), 0, stream>>>(
        hidden, target, node_W, node_b, path_nodes, path_bits, path_mask,
        partial, counter, out, D, T);
}

// Round 5
// 114.837 us; speedup vs baseline: 1.6301x; 1.6301x over previous
//
#include <hip/hip_runtime.h>

#define HID 768
#define NTHREADS 256
#define WPB 4          // waves per block = steps processed in parallel per token
#define RTHREADS 256   // reduce kernel block size

// One block per token t; wave w handles path steps d = w, w+4, w+8, ...
//
// v5 -> v6: REVERT the last-block fusion. v5's AGENT-scope ACQ_REL atomics
// forced per-XCD L2 invalidate/writeback on every block (8 XCD L2s are not
// cross-coherent), destroying W-row L2 reuse: step kernel 25 -> 105 us at
// 5% HBM. Back to the v4 two-kernel structure (no device-scope atomics in
// the hot path). Kept from v5 (verified absmax 0.0): the in-block LDS
// combine (w0+w1)+(w2+w3) -> ONE partial per token, so the reduce kernel
// reads 8 KB instead of 32 KB and the counter memset disappears.
__global__ __launch_bounds__(NTHREADS, 8) void huffman_token_kernel(
    const float* __restrict__ hidden,       // [T, H]
    const int*   __restrict__ target,       // [T]
    const float* __restrict__ node_W,       // [V-1, H, 2]
    const float* __restrict__ node_b,       // [V-1, 2]
    const int*   __restrict__ path_nodes,   // [V, D]
    const int*   __restrict__ path_bits,    // [V, D]
    const void*  __restrict__ path_mask,    // [V, D] bool (byte OR int32 layout)
    float*       __restrict__ partial,      // [T] one partial per token
    int D)
{
    const int t    = blockIdx.x;
    const int wave = threadIdx.x >> 6;
    const int lane = threadIdx.x & 63;

    __shared__ float ws4[WPB];

    // Mask layout detect: mask[0,0..3] all true (min Huffman depth >> 4),
    // so byte layout reads 0x01010101, int32 layout reads 1.
    const bool mask_is_byte = (*(const unsigned int*)path_mask) > 1u;

    const int v = target[t];                     // block-uniform scalar
    const long pbase = (long)v * D;

    // Per-lane path metadata: lane d owns step d (requires D <= 64; here ~20).
    bool  my_m = false;
    int   my_n = 0, my_bit = 0;
    float my_b0 = 0.0f, my_b1 = 0.0f;
    if (lane < D) {
        my_m = mask_is_byte
            ? (((const unsigned char*)path_mask)[pbase + lane] != 0)
            : (((const int*)path_mask)[pbase + lane] != 0);
        if (my_m) {
            my_n   = path_nodes[pbase + lane];
            my_bit = path_bits[pbase + lane];
            const float2 b2 = ((const float2*)node_b)[my_n];
            my_b0 = b2.x; my_b1 = b2.y;
        }
    }
    const int depth = __popcll(__ballot(my_m));  // mask is a prefix in d

    // h[t] into registers: lane owns k-pairs p = j*64 + lane (k = 2p, 2p+1).
    const float2* __restrict__ h2 = (const float2*)(hidden + (long)t * HID);
    float2 h[6];
    #pragma unroll
    for (int j = 0; j < 6; ++j) h[j] = h2[j * 64 + lane];

    float sum = 0.0f;

    for (int d = wave; d < depth; d += WPB) {
        // Wave-uniform per-step scalars straight into SGPRs.
        const int   n   = __builtin_amdgcn_readlane(my_n, d);
        const int   bit = __builtin_amdgcn_readlane(my_bit, d);
        const float b0  = __uint_as_float(
            __builtin_amdgcn_readlane(__float_as_uint(my_b0), d));
        const float b1  = __uint_as_float(
            __builtin_amdgcn_readlane(__float_as_uint(my_b1), d));

        const float4* __restrict__ w4 =
            (const float4*)(node_W + (long)n * (HID * 2));
        float4 w[6];
        #pragma unroll
        for (int j = 0; j < 6; ++j) w[j] = w4[j * 64 + lane];

        float acc0 = 0.0f, acc1 = 0.0f;
        #pragma unroll
        for (int j = 0; j < 6; ++j) {       // w = W[n,2p,{0,1}], W[n,2p+1,{0,1}]
            acc0 += h[j].x * w[j].x + h[j].y * w[j].z;
            acc1 += h[j].x * w[j].y + h[j].y * w[j].w;
        }

        // Packed 7-shuffle reduction (bit-identical to two 6-level butterflies).
        float r     = (lane < 32) ? acc0 : acc1;
        float other = (lane < 32) ? acc1 : acc0;
        r += __shfl_xor(other, 32, 64);     // fold lane^32 for both outputs
        #pragma unroll
        for (int off = 16; off > 0; off >>= 1) r += __shfl_xor(r, off, 64);
        const float ro = __shfl_xor(r, 32, 64);
        const float A0 = (lane < 32) ? r  : ro;
        const float A1 = (lane < 32) ? ro : r;

        // Double-softmax CE (faithful to reference), redundant per lane.
        const float l0  = A0 + b0;
        const float l1  = A1 + b1;
        const float m   = fmaxf(l0, l1);
        const float e0  = __expf(l0 - m);
        const float e1  = __expf(l1 - m);
        const float s   = e0 + e1;
        const float p0  = e0 / s;
        const float p1  = e1 / s;
        const float lse = __logf(__expf(p0) + __expf(p1));
        const float pb  = bit ? p1 : p0;
        sum += lse - pb;
    }

    // Cross-wave combine (plain LDS + plain store, no atomics):
    // token partial = (w0+w1)+(w2+w3) — tree verified bit-exact in v5.
    if (lane == 0) ws4[wave] = sum;
    __syncthreads();
    if (threadIdx.x == 0)
        partial[t] = (ws4[0] + ws4[1]) + (ws4[2] + ws4[3]);
}

// Single-block reduce of n floats (n % 4 == 0) -> out[0].  n = T = 2048:
// each thread sums float4 chunks {tid, tid+256} ascending, then butterfly.
__global__ __launch_bounds__(RTHREADS) void huffman_reduce_kernel(
    const float* __restrict__ partial, float* __restrict__ out, int n4)
{
    const float4* __restrict__ p4 = (const float4*)partial;
    float s = 0.0f;
    for (int i = threadIdx.x; i < n4; i += RTHREADS) {
        const float4 v = p4[i];
        s += (v.x + v.y) + (v.z + v.w);
    }
    #pragma unroll
    for (int off = 32; off > 0; off >>= 1) s += __shfl_xor(s, off, 64);
    __shared__ float ws[RTHREADS / 64];
    if ((threadIdx.x & 63) == 0) ws[threadIdx.x >> 6] = s;
    __syncthreads();
    if (threadIdx.x == 0) {
        float tot = 0.0f;
        #pragma unroll
        for (int w = 0; w < RTHREADS / 64; ++w) tot += ws[w];
        out[0] = tot;
    }
}

extern "C" void kernel_launch(void* const* d_in, const int* in_sizes, int n_in,
                              void* d_out, int out_size, void* d_ws, size_t ws_size,
                              hipStream_t stream) {
    const float* hidden     = (const float*)d_in[0];
    const int*   target     = (const int*)d_in[1];
    const float* node_W     = (const float*)d_in[2];
    const float* node_b     = (const float*)d_in[3];
    const int*   path_nodes = (const int*)d_in[4];
    const int*   path_bits  = (const int*)d_in[5];
    const void*  path_mask  = (const void*)d_in[6];
    float* out = (float*)d_out;
    float* partial = (float*)d_ws;

    const int T   = in_sizes[0] / HID;        // B*S = 2048 (in_sizes are elem counts)
    const int Vm1 = in_sizes[3] / 2;          // V-1
    const int V   = Vm1 + 1;
    const int D   = in_sizes[4] / V;          // padded path depth (~20)

    huffman_token_kernel<<<dim3(T), dim3(NTHREADS), 0, stream>>>(
        hidden, target, node_W, node_b, path_nodes, path_bits, path_mask,
        partial, D);

    huffman_reduce_kernel<<<dim3(1), dim3(RTHREADS), 0, stream>>>(
        partial, out, T / 4);
}